// Round 1
// baseline (466.625 us; speedup 1.0000x reference)
//
#include <hip/hip_runtime.h>
#include <cstdint>
#include <cstddef>

using u16 = unsigned short;
using bf16x8 = __attribute__((ext_vector_type(8))) __bf16;
using f32x4  = __attribute__((ext_vector_type(4))) float;

static __device__ __forceinline__ u16 f2bf(float f) {
  unsigned u = __builtin_bit_cast(unsigned, f);
  unsigned r = (u + 0x7fffu + ((u >> 16) & 1u)) >> 16;  // RNE
  return (u16)r;
}
static __device__ __forceinline__ float bf2f(u16 h) {
  unsigned u = ((unsigned)h) << 16;
  return __builtin_bit_cast(float, u);
}
static __device__ __forceinline__ float eluf(float x) {
  return x > 0.f ? x : expm1f(x);
}
static __device__ __forceinline__ void gload16(const u16* g, u16* l) {
  __builtin_amdgcn_global_load_lds(
      (const __attribute__((address_space(1))) void*)g,
      (__attribute__((address_space(3))) void*)l, 16, 0, 0);
}

// ---------------------------------------------------------------------------
// Weight transpose+convert: src (E, Ksrc, Nsrc) f32  ->  dst bf16 (Nsrc*E, Kpad)
// dst row n' = dout*E + e (expert-interleaved), zero-padded for k >= Ksrc.
// ---------------------------------------------------------------------------
__global__ void transpose_convert(const float* __restrict__ src, u16* __restrict__ dst,
                                  int Ksrc, int Nsrc, int Kpad, int E) {
  __shared__ float tile[32][33];
  const int e  = blockIdx.z;
  const int k0 = blockIdx.x * 32;
  const int d0 = blockIdx.y * 32;
  const int tx = threadIdx.x;  // 0..31
  const int ty = threadIdx.y;  // 0..7
  const float* s = src + (size_t)e * Ksrc * Nsrc;
#pragma unroll
  for (int i = 0; i < 4; ++i) {
    const int k = k0 + ty + i * 8;
    float v = 0.f;
    if (k < Ksrc) v = s[(size_t)k * Nsrc + d0 + tx];
    tile[ty + i * 8][tx] = v;
  }
  __syncthreads();
#pragma unroll
  for (int i = 0; i < 4; ++i) {
    const int d = d0 + ty + i * 8;
    dst[((size_t)d * E + e) * Kpad + k0 + tx] = f2bf(tile[tx][ty + i * 8]);
  }
}

// ---------------------------------------------------------------------------
// Build bf16 concat buffers:
//   catP  (8192 x 288): [z(256) | p(16) | 0(16)]
//   catE0 (8192 x 544): [z(256) | v(3) | x_curr(256) | 0(29)]
//   cat0, cat1 (8192 x 768): [z(256) | <filled later>]
// ---------------------------------------------------------------------------
__global__ void prep_cat(const float* __restrict__ z, const float* __restrict__ p,
                         const float* __restrict__ vh, const float* __restrict__ xc,
                         u16* __restrict__ catP, u16* __restrict__ catE0,
                         u16* __restrict__ cat0, u16* __restrict__ cat1) {
  const int m = blockIdx.x;
  const int t = threadIdx.x;  // 0..255
  const u16 zb = f2bf(z[(size_t)m * 256 + t]);
  catP [(size_t)m * 288 + t] = zb;
  catE0[(size_t)m * 544 + t] = zb;
  cat0 [(size_t)m * 768 + t] = zb;
  cat1 [(size_t)m * 768 + t] = zb;
  if (t < 32) {
    const u16 val = (t < 16) ? f2bf(p[(size_t)m * 16 + t]) : (u16)0;
    catP[(size_t)m * 288 + 256 + t] = val;
  }
  for (int c = 256 + t; c < 544; c += 256) {
    const int idx = c - 256;
    float v = 0.f;
    if (idx < 3)        v = vh[(size_t)m * 3 + idx];
    else if (idx < 259) v = xc[(size_t)m * 256 + (idx - 3)];
    catE0[(size_t)m * 544 + c] = f2bf(v);
  }
}

// ---------------------------------------------------------------------------
// Gating layer 2 (N=8) + softmax: one wave per token.
// ---------------------------------------------------------------------------
__global__ __launch_bounds__(256) void gating_tail(const u16* __restrict__ cat,
                                                   const float* __restrict__ gw2,
                                                   const float* __restrict__ gb2,
                                                   float* __restrict__ ew) {
  const int ln = threadIdx.x & 63;
  const int token = (int)((blockIdx.x * 256 + threadIdx.x) >> 6);
  const u16* row = cat + (size_t)token * 768;
  float a[8] = {0.f, 0.f, 0.f, 0.f, 0.f, 0.f, 0.f, 0.f};
#pragma unroll
  for (int kk = 0; kk < 12; ++kk) {
    const int k = kk * 64 + ln;
    const float x = bf2f(row[k]);
    const float4* wr = reinterpret_cast<const float4*>(gw2 + (size_t)k * 8);
    const float4 w0 = wr[0], w1 = wr[1];
    a[0] += x * w0.x; a[1] += x * w0.y; a[2] += x * w0.z; a[3] += x * w0.w;
    a[4] += x * w1.x; a[5] += x * w1.y; a[6] += x * w1.z; a[7] += x * w1.w;
  }
#pragma unroll
  for (int j = 0; j < 8; ++j) {
#pragma unroll
    for (int d = 32; d > 0; d >>= 1) a[j] += __shfl_xor(a[j], d);
    a[j] += gb2[j];
  }
  float mx = a[0];
#pragma unroll
  for (int j = 1; j < 8; ++j) mx = fmaxf(mx, a[j]);
  float s = 0.f, pj[8];
#pragma unroll
  for (int j = 0; j < 8; ++j) { pj[j] = expf(a[j] - mx); s += pj[j]; }
  const float inv = 1.f / s;
  if (ln == 0) {
#pragma unroll
    for (int j = 0; j < 8; ++j) ew[(size_t)token * 8 + j] = pj[j] * inv;
  }
}

// ---------------------------------------------------------------------------
// bf16 MFMA GEMM, 128x128 tile, 4 waves, BK=32, global_load_lds staging.
//   A  (M x K) bf16 row-major, row stride = K
//   Bt (N x K) bf16 row-major (i.e. W^T), row stride = K
// MODE 0: plain.  out bf16 at [m][out_col0+n] stride out_stride; +bias[n]; elu.
// MODE 1: expert. n = dout*8 + e; out = elu(sum_e ew[m,e]*(acc+bias[e*Dout+dout]));
//                 bf16 write at [m][out_col0+dout].
// MODE 2: expert, final: fp32 write to out[m*out_stride + dout], no elu.
// ---------------------------------------------------------------------------
template <int MODE>
__global__ __launch_bounds__(256) void gemm_mfma(
    const u16* __restrict__ A, const u16* __restrict__ Bt,
    const float* __restrict__ bias, const float* __restrict__ ew,
    void* __restrict__ outp, int M, int N, int K,
    int out_stride, int out_col0) {
  __shared__ alignas(16) u16 As[128 * 32];
  __shared__ alignas(16) u16 Bs[128 * 32];

  const int tid = threadIdx.x;
  const int ln  = tid & 63;
  const int wv  = tid >> 6;       // 0..3
  const int wr  = wv >> 1;        // wave row (0..1)
  const int wc  = wv & 1;         // wave col (0..1)
  const int m0  = blockIdx.y * 128;
  const int n0  = blockIdx.x * 128;

  // staging: each wave loads 2 chunks (16 rows x 32 cols = 1KB) of A and of B
  const int c0 = wv * 2;
  const int sr = ln >> 2;          // row within chunk
  const int sc = (ln & 3) * 8;     // u16 col within 32
  const u16* gA0 = A  + (size_t)(m0 + c0 * 16 + sr) * K + sc;
  const u16* gA1 = gA0 + (size_t)16 * K;
  const u16* gB0 = Bt + (size_t)(n0 + c0 * 16 + sr) * K + sc;
  const u16* gB1 = gB0 + (size_t)16 * K;
  u16* lA0 = &As[(size_t)c0 * 512];
  u16* lA1 = &As[(size_t)(c0 + 1) * 512];
  u16* lB0 = &Bs[(size_t)c0 * 512];
  u16* lB1 = &Bs[(size_t)(c0 + 1) * 512];

  f32x4 acc[4][4];
#pragma unroll
  for (int i = 0; i < 4; ++i)
#pragma unroll
    for (int j = 0; j < 4; ++j) acc[i][j] = (f32x4){0.f, 0.f, 0.f, 0.f};

  const int ar = ln & 15;          // fragment row within 16
  const int ak = (ln >> 4) * 8;    // k offset within 32

  const int kIters = K >> 5;
  for (int kt = 0; kt < kIters; ++kt) {
    gload16(gA0, lA0);
    gload16(gA1, lA1);
    gload16(gB0, lB0);
    gload16(gB1, lB1);
    gA0 += 32; gA1 += 32; gB0 += 32; gB1 += 32;
    __syncthreads();  // drains vmcnt(0): staged tile visible to all waves

    bf16x8 af[4], bfv[4];
#pragma unroll
    for (int i = 0; i < 4; ++i)
      af[i] = *reinterpret_cast<const bf16x8*>(&As[(size_t)(wr * 64 + i * 16 + ar) * 32 + ak]);
#pragma unroll
    for (int j = 0; j < 4; ++j)
      bfv[j] = *reinterpret_cast<const bf16x8*>(&Bs[(size_t)(wc * 64 + j * 16 + ar) * 32 + ak]);
#pragma unroll
    for (int i = 0; i < 4; ++i)
#pragma unroll
      for (int j = 0; j < 4; ++j)
        acc[i][j] = __builtin_amdgcn_mfma_f32_16x16x32_bf16(af[i], bfv[j], acc[i][j], 0, 0, 0);
    __syncthreads();  // all waves done reading before next stage overwrites
  }

  // Epilogue. C/D layout: col = lane&15, row = (lane>>4)*4 + reg.
  const int m0w = m0 + wr * 64 + (ln >> 4) * 4;
  const int n0w = n0 + wc * 64 + (ln & 15);

  if (MODE == 0) {
    u16* outb = (u16*)outp;
#pragma unroll
    for (int j = 0; j < 4; ++j) {
      const int n = n0w + j * 16;
      const float bv = bias[n];
#pragma unroll
      for (int i = 0; i < 4; ++i) {
#pragma unroll
        for (int r = 0; r < 4; ++r) {
          const int m = m0w + i * 16 + r;
          outb[(size_t)m * out_stride + out_col0 + n] = f2bf(eluf(acc[i][j][r] + bv));
        }
      }
    }
  } else {
    const int Dout = N >> 3;
#pragma unroll
    for (int j = 0; j < 4; ++j) {
      const int n = n0w + j * 16;
      const int e = n & 7;
      const int dout = n >> 3;
      const float bv = bias[(size_t)e * Dout + dout];
#pragma unroll
      for (int i = 0; i < 4; ++i) {
#pragma unroll
        for (int r = 0; r < 4; ++r) {
          const int m = m0w + i * 16 + r;
          float v = (acc[i][j][r] + bv) * ew[(size_t)m * 8 + e];
          v += __shfl_xor(v, 1);
          v += __shfl_xor(v, 2);
          v += __shfl_xor(v, 4);
          if ((ln & 7) == 0) {
            if (MODE == 1) {
              ((u16*)outp)[(size_t)m * out_stride + out_col0 + dout] = f2bf(eluf(v));
            } else {
              ((float*)outp)[(size_t)m * out_stride + dout] = v;
            }
          }
        }
      }
    }
  }
}

// ---------------------------------------------------------------------------
extern "C" void kernel_launch(void* const* d_in, const int* in_sizes, int n_in,
                              void* d_out, int out_size, void* d_ws, size_t ws_size,
                              hipStream_t stream) {
  const float* z   = (const float*)d_in[0];
  const float* p   = (const float*)d_in[1];
  const float* vh  = (const float*)d_in[2];
  const float* xc  = (const float*)d_in[3];
  const float* gw0 = (const float*)d_in[4];
  const float* gb0 = (const float*)d_in[5];
  const float* gw1 = (const float*)d_in[6];
  const float* gb1 = (const float*)d_in[7];
  const float* gw2 = (const float*)d_in[8];
  const float* gb2 = (const float*)d_in[9];
  const float* w0  = (const float*)d_in[10];
  const float* b0  = (const float*)d_in[11];
  const float* w1  = (const float*)d_in[12];
  const float* b1  = (const float*)d_in[13];
  const float* w2  = (const float*)d_in[14];
  const float* b2  = (const float*)d_in[15];
  const float* wo  = (const float*)d_in[16];
  const float* bo  = (const float*)d_in[17];
  float* out = (float*)d_out;

  char* ws = (char*)d_ws;
  size_t off = 0;
  auto alloc = [&](size_t bytes) {
    char* pp = ws + off;
    off += (bytes + 255) & ~(size_t)255;
    return pp;
  };
  u16* gw0t  = (u16*)alloc((size_t)512 * 288 * 2);
  u16* gw1t  = (u16*)alloc((size_t)512 * 768 * 2);
  u16* w0t   = (u16*)alloc((size_t)4096 * 544 * 2);
  u16* w1t   = (u16*)alloc((size_t)4096 * 768 * 2);
  u16* w2t   = (u16*)alloc((size_t)4096 * 768 * 2);
  u16* wot   = (u16*)alloc((size_t)2048 * 768 * 2);
  u16* catP  = (u16*)alloc((size_t)8192 * 288 * 2);
  u16* catE0 = (u16*)alloc((size_t)8192 * 544 * 2);
  u16* cat0  = (u16*)alloc((size_t)8192 * 768 * 2);
  u16* cat1  = (u16*)alloc((size_t)8192 * 768 * 2);
  float* ew  = (float*)alloc((size_t)8192 * 8 * 4);
  (void)ws_size; (void)in_sizes; (void)n_in; (void)out_size;

  const dim3 tb(32, 8);
  transpose_convert<<<dim3(9, 16, 1),  tb, 0, stream>>>(gw0, gw0t, 272, 512, 288, 1);
  transpose_convert<<<dim3(24, 16, 1), tb, 0, stream>>>(gw1, gw1t, 768, 512, 768, 1);
  transpose_convert<<<dim3(17, 16, 8), tb, 0, stream>>>(w0,  w0t,  515, 512, 544, 8);
  transpose_convert<<<dim3(24, 16, 8), tb, 0, stream>>>(w1,  w1t,  768, 512, 768, 8);
  transpose_convert<<<dim3(24, 16, 8), tb, 0, stream>>>(w2,  w2t,  768, 512, 768, 8);
  transpose_convert<<<dim3(24, 8, 8),  tb, 0, stream>>>(wo,  wot,  768, 256, 768, 8);
  prep_cat<<<8192, 256, 0, stream>>>(z, p, vh, xc, catP, catE0, cat0, cat1);

  // gating
  gemm_mfma<0><<<dim3(4, 64), 256, 0, stream>>>(catP, gw0t, gb0, nullptr, cat0,
                                                8192, 512, 288, 768, 256);
  gemm_mfma<0><<<dim3(4, 64), 256, 0, stream>>>(cat0, gw1t, gb1, nullptr, cat1,
                                                8192, 512, 768, 768, 256);
  gating_tail<<<2048, 256, 0, stream>>>(cat1, gw2, gb2, ew);

  // expert layers (expert-interleaved N)
  gemm_mfma<1><<<dim3(32, 64), 256, 0, stream>>>(catE0, w0t, b0, ew, cat0,
                                                 8192, 4096, 544, 768, 256);
  gemm_mfma<1><<<dim3(32, 64), 256, 0, stream>>>(cat0, w1t, b1, ew, cat1,
                                                 8192, 4096, 768, 768, 256);
  gemm_mfma<1><<<dim3(32, 64), 256, 0, stream>>>(cat1, w2t, b2, ew, cat0,
                                                 8192, 4096, 768, 768, 256);
  gemm_mfma<2><<<dim3(16, 64), 256, 0, stream>>>(cat0, wot, bo, ew, out,
                                                 8192, 2048, 768, 256, 0);
}